// Round 10
// baseline (215.148 us; speedup 1.0000x reference)
//
#include <hip/hip_runtime.h>
#include <hip/hip_bf16.h>
#include <cstdint>

// Problem: B=4, T=1024, C=1024, H=16, D=64, MAX_LEN=1024, NPOS=2047
// Pipeline (R25):
//   cvt3: x, qkv_w, proj_w fp32 -> bf16 in ws (measured ~96% HBM peak: done)
//   table_reduce rel_pos_emb -> (2047,16)  [R25: 1-wave-per-head, 1 tree]
//   gemm_bt<0>: qkv = xb @ qwb^T + b -> scatter bf16; Q,K (B,H,T,D), V (B,H,D,T)
//   attn_mfma: flash causal, 32x32 lane-local softmax, KVBLK=64 + defer-max
//   gemm_bt<1>: out = y @ pwb^T + b -> fp32 d_out
//
// R23 measured: total 193.4 (best). attn < 44.4us (out of top-5). gemm_bt<0>
// now the top dispatch: 44.5us = 580 TF, MfmaUtil 21%, VGPR 32 (!), occ 41%
// -- regressed from R12's 38.5us/VGPR 88 on identical source (rule #19
// co-compile perturbation) and was never the verified m97 shape anyway.
// R25 change: gemm_bt -> EXACT m97 structure (874-912 TF documented at this
// tile): 256 thr / 4 waves, each wave 64x64 output (acc[4][4], 16 MFMA per
// K-step per wave vs our old 8), BK=32, linear LDS [128][32], gload_lds 16B
// x2 per matrix per thread. Same 128^2 tile -> grid unchanged.
// table_reduce: 1024-thr blocks, wave w = head w: 1 coalesced load + single
// 6-shfl tree (was 4 serial trees) -> ~2.5us from 5.3.
//
// Workspace layout (bytes):
//   xb   @ 0         : 4096x1024 bf16  (8 MB)
//   qwb  @ 8388608   : 3072x1024 bf16  (6 MB)
//   pwb  @ 14680064  : 1024x1024 bf16  (2 MB)
//   table@ 16777216  : 2047x16 f32     (128 KB)
//   qkvb @ 16908288  : (3,4,16,64K) bf16 (24 MB)
//   y    @ 42074112  : 4096x1024 bf16  (8 MB)

typedef __bf16 bf16x8 __attribute__((ext_vector_type(8)));
typedef float f32x4 __attribute__((ext_vector_type(4)));
typedef float f32x16 __attribute__((ext_vector_type(16)));

__device__ __forceinline__ float bf2f(unsigned short u) {
    return __uint_as_float(((unsigned)u) << 16);
}
__device__ __forceinline__ unsigned short f2bf(float f) {
    __hip_bfloat16 h = __float2bfloat16(f);
    return *reinterpret_cast<unsigned short*>(&h);
}
__device__ __forceinline__ unsigned pk2(float a, float b) {
    return (unsigned)f2bf(a) | ((unsigned)f2bf(b) << 16);
}
__device__ __forceinline__ int4 cvt8(float4 a, float4 b) {
    union { unsigned short s[8]; int4 v; } u;
    u.s[0] = f2bf(a.x); u.s[1] = f2bf(a.y); u.s[2] = f2bf(a.z); u.s[3] = f2bf(a.w);
    u.s[4] = f2bf(b.x); u.s[5] = f2bf(b.y); u.s[6] = f2bf(b.z); u.s[7] = f2bf(b.w);
    return u.v;
}

// async global->LDS, 16B per lane. LDS dest must be linear base+lane*16.
__device__ __forceinline__ void gload16(const void* g, void* l) {
    __builtin_amdgcn_global_load_lds(
        reinterpret_cast<const __attribute__((address_space(1))) unsigned int*>(
            reinterpret_cast<uintptr_t>(g)),
        reinterpret_cast<__attribute__((address_space(3))) unsigned int*>(
            reinterpret_cast<uintptr_t>(l)),
        16, 0, 0);
}

// ---------------- fp32 -> bf16 one-shot convert (x, qkv_w, proj_w) ----------
__global__ __launch_bounds__(256) void cvt3(const float* __restrict__ x,
                                            const float* __restrict__ w1,
                                            const float* __restrict__ w2,
                                            unsigned short* __restrict__ ox,
                                            unsigned short* __restrict__ ow1,
                                            unsigned short* __restrict__ ow2) {
    const int i = blockIdx.x * 256 + threadIdx.x;
    const float* s; unsigned short* d; int li;
    if (i < 524288)      { s = x;  d = ox;  li = i; }
    else if (i < 917504) { s = w1; d = ow1; li = i - 524288; }
    else                 { s = w2; d = ow2; li = i - 917504; }
    const float4 a = *(const float4*)(s + (size_t)li * 8);
    const float4 b = *(const float4*)(s + (size_t)li * 8 + 4);
    *(int4*)(d + (size_t)li * 8) = cvt8(a, b);
}

// ---------------- rel_pos_emb (2047,1024) -> table (2047,16) ----------------
// R25: 1024 thr = 16 waves; wave w sums head w's 64 d's: coalesced load +
// single 6-shfl tree (was 4 serial trees per wave).
__global__ __launch_bounds__(1024) void table_reduce(const float* __restrict__ rel,
                                                     float* __restrict__ table) {
    const int p = blockIdx.x;
    const int w = threadIdx.x >> 6, lane = threadIdx.x & 63;
    float v = rel[(size_t)p * 1024 + w * 64 + lane];
#pragma unroll
    for (int o = 32; o; o >>= 1) v += __shfl_xor(v, o, 64);
    if (lane == 0) table[p * 16 + w] = v;
}

// ---------------- bf16 MFMA GEMM: C = A B^T + bias (EXACT m97 shape) -------
// 256 threads, 4 waves: wr=wave&1 (64-row half), wc=wave>>1 (64-col half).
// Each wave: 64x64 output = acc[4][4], 16 MFMA per K-step. BK=32.
// Staging: thread t covers LDS shorts [t*8..t*8+8) and [2048+t*8..) per
// matrix (rows t>>2 and 64+(t>>2), cols (t&3)*8) -- linear, gload_lds 16B.
// EPI=0: scatter bf16 into qkv planes (Q,K [t][d], V [d][t]). EPI=1: fp32 out.
template <int EPI>
__global__ __launch_bounds__(256) void gemm_bt(const unsigned short* __restrict__ A,
                                               const unsigned short* __restrict__ B,
                                               const float* __restrict__ bias,
                                               unsigned short* __restrict__ outb,
                                               float* __restrict__ outf,
                                               int M, int N, int K) {
    __shared__ __attribute__((aligned(16))) unsigned short As[128 * 32];
    __shared__ __attribute__((aligned(16))) unsigned short Bs[128 * 32];
    const int bm = blockIdx.x * 128, bn = blockIdx.y * 128;
    const int tid = threadIdx.x, lane = tid & 63, wave = tid >> 6;  // 0..3
    const int wr = wave & 1, wc = wave >> 1;  // each 0..1
    const int quad = lane >> 4, lm = lane & 15;

    const int srow = tid >> 2;        // 0..63
    const int scol = (tid & 3) * 8;   // shorts
    const unsigned short* Ap0 = A + (size_t)(bm + srow) * K + scol;
    const unsigned short* Ap1 = A + (size_t)(bm + 64 + srow) * K + scol;
    const unsigned short* Bp0 = B + (size_t)(bn + srow) * K + scol;
    const unsigned short* Bp1 = B + (size_t)(bn + 64 + srow) * K + scol;
    unsigned short* AsW0 = &As[tid * 8];          // rows 0..63 linear
    unsigned short* AsW1 = &As[2048 + tid * 8];   // rows 64..127
    unsigned short* BsW0 = &Bs[tid * 8];
    unsigned short* BsW1 = &Bs[2048 + tid * 8];

    f32x4 acc[4][4];
#pragma unroll
    for (int r = 0; r < 4; ++r)
#pragma unroll
        for (int c = 0; c < 4; ++c) acc[r][c] = (f32x4){0.f, 0.f, 0.f, 0.f};

    for (int kk = 0; kk < K; kk += 32) {
        gload16(Ap0 + kk, AsW0);
        gload16(Ap1 + kk, AsW1);
        gload16(Bp0 + kk, BsW0);
        gload16(Bp1 + kk, BsW1);
        __syncthreads();  // compiler emits vmcnt(0) drain before s_barrier

        bf16x8 af[4], bfr[4];
#pragma unroll
        for (int r = 0; r < 4; ++r)
            af[r] = *(const bf16x8*)(&As[(64 * wr + 16 * r + lm) * 32 + quad * 8]);
#pragma unroll
        for (int c = 0; c < 4; ++c)
            bfr[c] = *(const bf16x8*)(&Bs[(64 * wc + 16 * c + lm) * 32 + quad * 8]);
#pragma unroll
        for (int r = 0; r < 4; ++r)
#pragma unroll
            for (int c = 0; c < 4; ++c)
                acc[r][c] = __builtin_amdgcn_mfma_f32_16x16x32_bf16(af[r], bfr[c], acc[r][c], 0, 0, 0);
        __syncthreads();
    }

    // C/D layout: col = lane&15, row = (lane>>4)*4 + reg
#pragma unroll
    for (int r = 0; r < 4; ++r)
#pragma unroll
        for (int c = 0; c < 4; ++c)
#pragma unroll
            for (int i = 0; i < 4; ++i) {
                const int row = bm + 64 * wr + 16 * r + quad * 4 + i;
                const int col = bn + 64 * wc + 16 * c + lm;
                const float v = acc[r][c][i] + bias[col];
                if (EPI == 0) {
                    const int b = row >> 10, t = row & 1023;
                    const int s3 = col >> 10, rem = col & 1023;
                    const int h = rem >> 6, d = rem & 63;
                    const size_t base = (((size_t)s3 * 4 + b) * 16 + h) * 65536;
                    const size_t off = base + (s3 == 2 ? (size_t)d * 1024 + t
                                                       : (size_t)t * 64 + d);
                    outb[off] = f2bf(v);
                } else {
                    outf[(size_t)row * N + col] = v;
                }
            }
}

// ---------------- MFMA flash causal attention (unchanged from R23) ---------
// 32x32 lane-local softmax, KVBLK=64 joint tiles + T13 defer-max.
#define LOADK(DST, KT)                                                        \
    do {                                                                      \
        const unsigned short* kr_ = Kg + (size_t)((KT) * 32 + l5) * 64 + hi8; \
        DST[0] = *(const bf16x8*)(kr_);                                       \
        DST[1] = *(const bf16x8*)(kr_ + 16);                                  \
        DST[2] = *(const bf16x8*)(kr_ + 32);                                  \
        DST[3] = *(const bf16x8*)(kr_ + 48);                                  \
    } while (0)

// Single 32-j tile (tail only; always-rescale path). Uses kA-style frag KF.
#define ATTN_TILE(KF, KT)                                                     \
    do {                                                                      \
        const int jb = (KT) * 32;                                             \
        const unsigned short* vb_ = Vtg + (size_t)l5 * 1024 + jb + hi8;       \
        const bf16x8 vf00 = *(const bf16x8*)(vb_);                            \
        const bf16x8 vf01 = *(const bf16x8*)(vb_ + 16);                       \
        const bf16x8 vf10 = *(const bf16x8*)(vb_ + 32768);                    \
        const bf16x8 vf11 = *(const bf16x8*)(vb_ + 32768 + 16);               \
        f32x16 s = {0.f};                                                     \
        _Pragma("unroll")                                                     \
        for (int t = 0; t < 4; ++t)                                           \
            s = __builtin_amdgcn_mfma_f32_32x32x16_bf16(KF[t], qf[t], s, 0, 0, 0); \
        float p[16];                                                          \
        _Pragma("unroll")                                                     \
        for (int reg = 0; reg < 16; ++reg) {                                  \
            const int j = jb + (reg & 3) + 8 * (reg >> 2) + 4 * hi;           \
            p[reg] = fmaf(s[reg], 0.125f, tb[q - j + 127]);                   \
        }                                                                     \
        if (jb + 31 > qbase) {                                                \
            _Pragma("unroll")                                                 \
            for (int reg = 0; reg < 16; ++reg) {                              \
                const int j = jb + (reg & 3) + 8 * (reg >> 2) + 4 * hi;       \
                p[reg] = (j <= q) ? p[reg] : -1e30f;                          \
            }                                                                 \
        }                                                                     \
        float mx = p[0];                                                      \
        _Pragma("unroll")                                                     \
        for (int reg = 1; reg < 16; ++reg) mx = fmaxf(mx, p[reg]);            \
        mx = fmaxf(mx, __shfl_xor(mx, 32, 64));                               \
        if (!__all(mx <= mi + 8.f)) {                                         \
            const float mnew = fmaxf(mi, mx);                                 \
            const float alpha = __expf(mi - mnew);                            \
            mi = mnew;                                                        \
            li *= alpha;                                                      \
            _Pragma("unroll")                                                 \
            for (int reg = 0; reg < 16; ++reg) {                              \
                oa0[reg] *= alpha;                                            \
                oa1[reg] *= alpha;                                            \
            }                                                                 \
        }                                                                     \
        float lsum = 0.f;                                                     \
        _Pragma("unroll")                                                     \
        for (int reg = 0; reg < 16; ++reg) {                                  \
            p[reg] = __expf(p[reg] - mi);                                     \
            lsum += p[reg];                                                   \
        }                                                                     \
        li += lsum;                                                           \
        const unsigned P0 = pk2(p[0], p[1]),   P1 = pk2(p[2], p[3]);          \
        const unsigned P2 = pk2(p[4], p[5]),   P3 = pk2(p[6], p[7]);          \
        const unsigned P4 = pk2(p[8], p[9]),   P5 = pk2(p[10], p[11]);        \
        const unsigned P6 = pk2(p[12], p[13]), P7 = pk2(p[14], p[15]);        \
        const unsigned R0 = __shfl_xor(hi ? P0 : P2, 32, 64);                 \
        const unsigned R1 = __shfl_xor(hi ? P1 : P3, 32, 64);                 \
        const unsigned R2 = __shfl_xor(hi ? P4 : P6, 32, 64);                 \
        const unsigned R3 = __shfl_xor(hi ? P5 : P7, 32, 64);                 \
        union { unsigned w[4]; bf16x8 v; } bq0, bq1;                          \
        bq0.w[0] = hi ? R0 : P0;  bq0.w[1] = hi ? R1 : P1;                    \
        bq0.w[2] = hi ? P2 : R0;  bq0.w[3] = hi ? P3 : R1;                    \
        bq1.w[0] = hi ? R2 : P4;  bq1.w[1] = hi ? R3 : P5;                    \
        bq1.w[2] = hi ? P6 : R2;  bq1.w[3] = hi ? P7 : R3;                    \
        oa0 = __builtin_amdgcn_mfma_f32_32x32x16_bf16(vf00, bq0.v, oa0, 0, 0, 0); \
        oa0 = __builtin_amdgcn_mfma_f32_32x32x16_bf16(vf01, bq1.v, oa0, 0, 0, 0); \
        oa1 = __builtin_amdgcn_mfma_f32_32x32x16_bf16(vf10, bq0.v, oa1, 0, 0, 0); \
        oa1 = __builtin_amdgcn_mfma_f32_32x32x16_bf16(vf11, bq1.v, oa1, 0, 0, 0); \
    } while (0)

// Pack+partner-exchange p[16] -> two PV B-frags (BQA, BQB).
#define PACKP(p, BQA, BQB)                                                    \
    do {                                                                      \
        const unsigned P0 = pk2(p[0], p[1]),   P1 = pk2(p[2], p[3]);          \
        const unsigned P2 = pk2(p[4], p[5]),   P3 = pk2(p[6], p[7]);          \
        const unsigned P4 = pk2(p[8], p[9]),   P5 = pk2(p[10], p[11]);        \
        const unsigned P6 = pk2(p[12], p[13]), P7 = pk2(p[14], p[15]);        \
        const unsigned R0 = __shfl_xor(hi ? P0 : P2, 32, 64);                 \
        const unsigned R1 = __shfl_xor(hi ? P1 : P3, 32, 64);                 \
        const unsigned R2 = __shfl_xor(hi ? P4 : P6, 32, 64);                 \
        const unsigned R3 = __shfl_xor(hi ? P5 : P7, 32, 64);                 \
        BQA.w[0] = hi ? R0 : P0;  BQA.w[1] = hi ? R1 : P1;                    \
        BQA.w[2] = hi ? P2 : R0;  BQA.w[3] = hi ? P3 : R1;                    \
        BQB.w[0] = hi ? R2 : P4;  BQB.w[1] = hi ? R3 : P5;                    \
        BQB.w[2] = hi ? P6 : R2;  BQB.w[3] = hi ? P7 : R3;                    \
    } while (0)

// Joint KVBLK=64: subtiles KT (kA) and KT+1 (kB); ONE softmax update.
#define ATTN_TILE2(KT)                                                        \
    do {                                                                      \
        const int jb = (KT) * 32;                                             \
        const unsigned short* vb_ = Vtg + (size_t)l5 * 1024 + jb + hi8;       \
        const bf16x8 vf00 = *(const bf16x8*)(vb_);                            \
        const bf16x8 vf01 = *(const bf16x8*)(vb_ + 16);                       \
        const bf16x8 vf02 = *(const bf16x8*)(vb_ + 32);                       \
        const bf16x8 vf03 = *(const bf16x8*)(vb_ + 48);                       \
        const bf16x8 vf10 = *(const bf16x8*)(vb_ + 32768);                    \
        const bf16x8 vf11 = *(const bf16x8*)(vb_ + 32768 + 16);               \
        const bf16x8 vf12 = *(const bf16x8*)(vb_ + 32768 + 32);               \
        const bf16x8 vf13 = *(const bf16x8*)(vb_ + 32768 + 48);               \
        f32x16 s0v = {0.f}, s1v = {0.f};                                      \
        _Pragma("unroll")                                                     \
        for (int t = 0; t < 4; ++t) {                                         \
            s0v = __builtin_amdgcn_mfma_f32_32x32x16_bf16(kA[t], qf[t], s0v, 0, 0, 0); \
            s1v = __builtin_amdgcn_mfma_f32_32x32x16_bf16(kB[t], qf[t], s1v, 0, 0, 0); \
        }                                                                     \
        if ((KT) + 2 < nt) LOADK(kA, (KT) + 2);                               \
        if ((KT) + 3 < nt) LOADK(kB, (KT) + 3);                               \
        float p0[16], p1[16];                                                 \
        _Pragma("unroll")                                                     \
        for (int reg = 0; reg < 16; ++reg) {                                  \
            const int jo = (reg & 3) + 8 * (reg >> 2) + 4 * hi;               \
            p0[reg] = fmaf(s0v[reg], 0.125f, tb[q - jb - jo + 127]);          \
            p1[reg] = fmaf(s1v[reg], 0.125f, tb[q - jb - 32 - jo + 127]);     \
        }                                                                     \
        if (jb + 63 > qbase) {                                                \
            _Pragma("unroll")                                                 \
            for (int reg = 0; reg < 16; ++reg) {                              \
                const int jo = (reg & 3) + 8 * (reg >> 2) + 4 * hi;           \
                p0[reg] = (jb + jo <= q) ? p0[reg] : -1e30f;                  \
                p1[reg] = (jb + 32 + jo <= q) ? p1[reg] : -1e30f;             \
            }                                                                 \
        }                                                                     \
        float mx = p0[0];                                                     \
        _Pragma("unroll")                                                     \
        for (int reg = 1; reg < 16; ++reg) mx = fmaxf(mx, p0[reg]);           \
        _Pragma("unroll")                                                     \
        for (int reg = 0; reg < 16; ++reg) mx = fmaxf(mx, p1[reg]);           \
        mx = fmaxf(mx, __shfl_xor(mx, 32, 64));                               \
        if (!__all(mx <= mi + 8.f)) {                                         \
            const float mnew = fmaxf(mi, mx);                                 \
            const float alpha = __expf(mi - mnew);                            \
            mi = mnew;                                                        \
            li *= alpha;                                                      \
            _Pragma("unroll")                                                 \
            for (int reg = 0; reg < 16; ++reg) {                              \
                oa0[reg] *= alpha;                                            \
                oa1[reg] *= alpha;                                            \
            }                                                                 \
        }                                                                     \
        float lsum = 0.f;                                                     \
        _Pragma("unroll")                                                     \
        for (int reg = 0; reg < 16; ++reg) {                                  \
            p0[reg] = __expf(p0[reg] - mi);                                   \
            p1[reg] = __expf(p1[reg] - mi);                                   \
            lsum += p0[reg] + p1[reg];                                        \
        }                                                                     \
        li += lsum;                                                           \
        union { unsigned w[4]; bf16x8 v; } bq00, bq01, bq10, bq11;            \
        PACKP(p0, bq00, bq01);                                                \
        PACKP(p1, bq10, bq11);                                                \
        oa0 = __builtin_amdgcn_mfma_f32_32x32x16_bf16(vf00, bq00.v, oa0, 0, 0, 0); \
        oa1 = __builtin_amdgcn_mfma_f32_32x32x16_bf16(vf10, bq00.v, oa1, 0, 0, 0); \
        oa0 = __builtin_amdgcn_mfma_f32_32x32x16_bf16(vf01, bq01.v, oa0, 0, 0, 0); \
        oa1 = __builtin_amdgcn_mfma_f32_32x32x16_bf16(vf11, bq01.v, oa1, 0, 0, 0); \
        oa0 = __builtin_amdgcn_mfma_f32_32x32x16_bf16(vf02, bq10.v, oa0, 0, 0, 0); \
        oa1 = __builtin_amdgcn_mfma_f32_32x32x16_bf16(vf12, bq10.v, oa1, 0, 0, 0); \
        oa0 = __builtin_amdgcn_mfma_f32_32x32x16_bf16(vf03, bq11.v, oa0, 0, 0, 0); \
        oa1 = __builtin_amdgcn_mfma_f32_32x32x16_bf16(vf13, bq11.v, oa1, 0, 0, 0); \
    } while (0)

__global__ __launch_bounds__(128) void attn_mfma(const unsigned short* __restrict__ qkvb,
                                                 const float* __restrict__ table,
                                                 unsigned short* __restrict__ y) {
    const int bh = blockIdx.x, b = bh >> 4, h = bh & 15;
    const int level = 15 - blockIdx.y;      // 15..0, longest blocks first
    const int tid = threadIdx.x, lane = tid & 63, wave = tid >> 6;  // wave 0..1
    const int l5 = lane & 31, hi = lane >> 5, hi8 = hi * 8;

    __shared__ float tb[1152];

    const unsigned short* Qg  = qkvb + ((size_t)(b)*16 + h) * 65536;       // [t][d]
    const unsigned short* Kg  = qkvb + ((size_t)(4 + b)*16 + h) * 65536;   // [t][d]
    const unsigned short* Vtg = qkvb + ((size_t)(8 + b)*16 + h) * 65536;   // [d][t]

    const int qbase = 64 * level + 32 * wave;
    const int q = qbase + l5;               // ONE query per lane
    const int nt = 2 * level + wave + 1;    // exact causal 32-j tile count

    // Q fragment (MFMA B-operand): B[col=q][k = t*16 + hi*8 + e]
    bf16x8 qf[4];
    {
        const unsigned short* qr = Qg + (size_t)q * 64 + hi8;
#pragma unroll
        for (int t = 0; t < 4; ++t) qf[t] = *(const bf16x8*)(qr + t * 16);
    }

    // tb[i] = table[(896+i)*16+h]; needed i = q-j+127 in [96, 64*level+190]
    const int tbn = 64 * level + 191;
    for (int i = tid; i < tbn; i += 128) tb[i] = table[(896 + i) * 16 + h];
    __syncthreads();  // tb ready; only block-wide sync in the kernel

    f32x16 oa0 = {0.f}, oa1 = {0.f};  // O^T d-halves: row d, col q (own lane)
    float mi = -1e30f, li = 0.f;

    bf16x8 kA[4], kB[4];
    LOADK(kA, 0);
    LOADK(kB, nt > 1 ? 1 : 0);
    int kt = 0;
    for (; kt + 1 < nt; kt += 2) ATTN_TILE2(kt);
    if (kt < nt) ATTN_TILE(kA, kt);  // odd-nt tail (kA prefetched by pair loop)

    // epilogue: li = own + partner halves (1 shfl); O^T/li -> y.
    li += __shfl_xor(li, 32, 64);
    const float linv = 1.0f / li;
    // lane's d = dh*32 + 8*g + 4*hi + (0..3)  (reg = 4g..4g+3 consecutive)
    unsigned short* yq = y + ((size_t)(b * 1024 + q)) * 1024 + h * 64;
#pragma unroll
    for (int g = 0; g < 4; ++g) {
        union { unsigned short u[4]; int2 v; } o4a, o4b;
#pragma unroll
        for (int i = 0; i < 4; ++i) {
            o4a.u[i] = f2bf(oa0[4 * g + i] * linv);
            o4b.u[i] = f2bf(oa1[4 * g + i] * linv);
        }
        *(int2*)(yq + 8 * g + 4 * hi) = o4a.v;
        *(int2*)(yq + 32 + 8 * g + 4 * hi) = o4b.v;
    }
}

extern "C" void kernel_launch(void* const* d_in, const int* in_sizes, int n_in,
                              void* d_out, int out_size, void* d_ws, size_t ws_size,
                              hipStream_t stream) {
    const float* x      = (const float*)d_in[0];
    const float* qkv_w  = (const float*)d_in[1];
    const float* qkv_b  = (const float*)d_in[2];
    const float* proj_w = (const float*)d_in[3];
    const float* proj_b = (const float*)d_in[4];
    const float* rel    = (const float*)d_in[5];
    float* out = (float*)d_out;

    char* ws = (char*)d_ws;
    unsigned short* xb   = (unsigned short*)(ws + 0);
    unsigned short* qwb  = (unsigned short*)(ws + 8388608);
    unsigned short* pwb  = (unsigned short*)(ws + 14680064);
    float* table         = (float*)(ws + 16777216);
    unsigned short* qkvb = (unsigned short*)(ws + 16908288);
    unsigned short* yb   = (unsigned short*)(ws + 42074112);

    cvt3<<<4096, 256, 0, stream>>>(x, qkv_w, proj_w, xb, qwb, pwb);
    table_reduce<<<2047, 1024, 0, stream>>>(rel, table);
    gemm_bt<0><<<dim3(32, 24), 256, 0, stream>>>(xb, qwb, qkv_b, qkvb, nullptr,
                                                 4096, 3072, 1024);
    attn_mfma<<<dim3(64, 16), 128, 0, stream>>>(qkvb, table, yb);
    gemm_bt<1><<<dim3(32, 8), 256, 0, stream>>>(yb, pwb, proj_b, nullptr, out,
                                                4096, 1024, 1024);
}

// Round 11
// 193.163 us; speedup vs baseline: 1.1138x; 1.1138x over previous
//
#include <hip/hip_runtime.h>
#include <hip/hip_bf16.h>
#include <cstdint>

// Problem: B=4, T=1024, C=1024, H=16, D=64, MAX_LEN=1024, NPOS=2047
// Pipeline (R27):
//   cvt3: x, qkv_w, proj_w fp32 -> bf16 in ws (measured ~96% HBM peak: done)
//   table_reduce rel_pos_emb -> (2047,16)  [1-wave-per-head]
//   gemm_bt<0>: qkv = xb @ qwb^T + b -> scatter bf16; Q,K (B,H,T,D), V (B,H,D,T)
//   attn_mfma: flash causal, 32x32 lane-local softmax, KVBLK=64 + defer-max
//   gemm_bt<1>: out = y @ pwb^T + b -> fp32 d_out
//
// R25 post-mortem: m97-shape gemm (256thr/4w/64x64) REGRESSED 44.5->68.2us
// (occ 13.8%: 768-block grid gives only 12 waves/CU with 4-wave blocks; m97's
// regime doesn't transfer to K=1024/768 blocks). R27 REVERTS gemm_bt to the
// R12-exact 512-thr/8-wave config (measured 38.5us R12 / 44.5us R23; occ up
// to 74.8%): wr=wave&1 64-row half, wc=wave>>1 32-col quarter, acc[4][2],
// linear LDS [128][32], gload_lds 16B x1 per matrix per thread, BK=32.
// table_reduce keeps R25's 1-wave-per-head form. attn unchanged from R23.
//
// Workspace layout (bytes):
//   xb   @ 0         : 4096x1024 bf16  (8 MB)
//   qwb  @ 8388608   : 3072x1024 bf16  (6 MB)
//   pwb  @ 14680064  : 1024x1024 bf16  (2 MB)
//   table@ 16777216  : 2047x16 f32     (128 KB)
//   qkvb @ 16908288  : (3,4,16,64K) bf16 (24 MB)
//   y    @ 42074112  : 4096x1024 bf16  (8 MB)

typedef __bf16 bf16x8 __attribute__((ext_vector_type(8)));
typedef float f32x4 __attribute__((ext_vector_type(4)));
typedef float f32x16 __attribute__((ext_vector_type(16)));

__device__ __forceinline__ float bf2f(unsigned short u) {
    return __uint_as_float(((unsigned)u) << 16);
}
__device__ __forceinline__ unsigned short f2bf(float f) {
    __hip_bfloat16 h = __float2bfloat16(f);
    return *reinterpret_cast<unsigned short*>(&h);
}
__device__ __forceinline__ unsigned pk2(float a, float b) {
    return (unsigned)f2bf(a) | ((unsigned)f2bf(b) << 16);
}
__device__ __forceinline__ int4 cvt8(float4 a, float4 b) {
    union { unsigned short s[8]; int4 v; } u;
    u.s[0] = f2bf(a.x); u.s[1] = f2bf(a.y); u.s[2] = f2bf(a.z); u.s[3] = f2bf(a.w);
    u.s[4] = f2bf(b.x); u.s[5] = f2bf(b.y); u.s[6] = f2bf(b.z); u.s[7] = f2bf(b.w);
    return u.v;
}

// async global->LDS, 16B per lane. LDS dest must be linear base+lane*16.
__device__ __forceinline__ void gload16(const void* g, void* l) {
    __builtin_amdgcn_global_load_lds(
        reinterpret_cast<const __attribute__((address_space(1))) unsigned int*>(
            reinterpret_cast<uintptr_t>(g)),
        reinterpret_cast<__attribute__((address_space(3))) unsigned int*>(
            reinterpret_cast<uintptr_t>(l)),
        16, 0, 0);
}

// ---------------- fp32 -> bf16 one-shot convert (x, qkv_w, proj_w) ----------
__global__ __launch_bounds__(256) void cvt3(const float* __restrict__ x,
                                            const float* __restrict__ w1,
                                            const float* __restrict__ w2,
                                            unsigned short* __restrict__ ox,
                                            unsigned short* __restrict__ ow1,
                                            unsigned short* __restrict__ ow2) {
    const int i = blockIdx.x * 256 + threadIdx.x;
    const float* s; unsigned short* d; int li;
    if (i < 524288)      { s = x;  d = ox;  li = i; }
    else if (i < 917504) { s = w1; d = ow1; li = i - 524288; }
    else                 { s = w2; d = ow2; li = i - 917504; }
    const float4 a = *(const float4*)(s + (size_t)li * 8);
    const float4 b = *(const float4*)(s + (size_t)li * 8 + 4);
    *(int4*)(d + (size_t)li * 8) = cvt8(a, b);
}

// ---------------- rel_pos_emb (2047,1024) -> table (2047,16) ----------------
// 1024 thr = 16 waves; wave w sums head w's 64 d's: coalesced load + single
// 6-shfl tree.
__global__ __launch_bounds__(1024) void table_reduce(const float* __restrict__ rel,
                                                     float* __restrict__ table) {
    const int p = blockIdx.x;
    const int w = threadIdx.x >> 6, lane = threadIdx.x & 63;
    float v = rel[(size_t)p * 1024 + w * 64 + lane];
#pragma unroll
    for (int o = 32; o; o >>= 1) v += __shfl_xor(v, o, 64);
    if (lane == 0) table[p * 16 + w] = v;
}

// ---------------- bf16 MFMA GEMM: C = A B^T + bias (R12-exact) --------------
// 512 threads, 8 waves: wr=wave&1 (64-row half), wc=wave>>1 (32-col quarter).
// Staging: global_load_lds width=16; thread t covers row t>>2, shorts (t&3)*8
// -> LDS linear [128][32]. One call per matrix per K-step (8 KB each).
// EPI=0: scatter bf16 into qkv planes (Q,K [t][d], V [d][t]). EPI=1: fp32 out.
template <int EPI>
__global__ __launch_bounds__(512) void gemm_bt(const unsigned short* __restrict__ A,
                                               const unsigned short* __restrict__ B,
                                               const float* __restrict__ bias,
                                               unsigned short* __restrict__ outb,
                                               float* __restrict__ outf,
                                               int M, int N, int K) {
    __shared__ __attribute__((aligned(16))) unsigned short As[128 * 32];
    __shared__ __attribute__((aligned(16))) unsigned short Bs[128 * 32];
    const int bm = blockIdx.x * 128, bn = blockIdx.y * 128;
    const int tid = threadIdx.x, lane = tid & 63, wave = tid >> 6;
    const int wr = wave & 1, wc = wave >> 1;  // wc in 0..3
    const int quad = lane >> 4, lm = lane & 15;

    const int srow = tid >> 2;        // 0..127
    const int scol = (tid & 3) * 8;   // shorts
    const unsigned short* Ap = A + (size_t)(bm + srow) * K + scol;
    const unsigned short* Bp = B + (size_t)(bn + srow) * K + scol;
    unsigned short* AsW = &As[tid * 8];   // == row srow, col scol (linear)
    unsigned short* BsW = &Bs[tid * 8];

    f32x4 acc[4][2];
#pragma unroll
    for (int r = 0; r < 4; ++r)
#pragma unroll
        for (int c = 0; c < 2; ++c) acc[r][c] = (f32x4){0.f, 0.f, 0.f, 0.f};

    for (int kk = 0; kk < K; kk += 32) {
        gload16(Ap + kk, AsW);
        gload16(Bp + kk, BsW);
        __syncthreads();  // compiler emits vmcnt(0) drain before s_barrier

        bf16x8 af[4], bfr[2];
#pragma unroll
        for (int r = 0; r < 4; ++r)
            af[r] = *(const bf16x8*)(&As[(64 * wr + 16 * r + lm) * 32 + quad * 8]);
#pragma unroll
        for (int c = 0; c < 2; ++c)
            bfr[c] = *(const bf16x8*)(&Bs[(32 * wc + 16 * c + lm) * 32 + quad * 8]);
#pragma unroll
        for (int r = 0; r < 4; ++r)
#pragma unroll
            for (int c = 0; c < 2; ++c)
                acc[r][c] = __builtin_amdgcn_mfma_f32_16x16x32_bf16(af[r], bfr[c], acc[r][c], 0, 0, 0);
        __syncthreads();
    }

    // C/D layout: col = lane&15, row = (lane>>4)*4 + reg
#pragma unroll
    for (int r = 0; r < 4; ++r)
#pragma unroll
        for (int c = 0; c < 2; ++c)
#pragma unroll
            for (int i = 0; i < 4; ++i) {
                const int row = bm + 64 * wr + 16 * r + quad * 4 + i;
                const int col = bn + 32 * wc + 16 * c + lm;
                const float v = acc[r][c][i] + bias[col];
                if (EPI == 0) {
                    const int b = row >> 10, t = row & 1023;
                    const int s3 = col >> 10, rem = col & 1023;
                    const int h = rem >> 6, d = rem & 63;
                    const size_t base = (((size_t)s3 * 4 + b) * 16 + h) * 65536;
                    const size_t off = base + (s3 == 2 ? (size_t)d * 1024 + t
                                                       : (size_t)t * 64 + d);
                    outb[off] = f2bf(v);
                } else {
                    outf[(size_t)row * N + col] = v;
                }
            }
}

// ---------------- MFMA flash causal attention (unchanged from R23) ---------
// 32x32 lane-local softmax, KVBLK=64 joint tiles + T13 defer-max.
#define LOADK(DST, KT)                                                        \
    do {                                                                      \
        const unsigned short* kr_ = Kg + (size_t)((KT) * 32 + l5) * 64 + hi8; \
        DST[0] = *(const bf16x8*)(kr_);                                       \
        DST[1] = *(const bf16x8*)(kr_ + 16);                                  \
        DST[2] = *(const bf16x8*)(kr_ + 32);                                  \
        DST[3] = *(const bf16x8*)(kr_ + 48);                                  \
    } while (0)

// Single 32-j tile (tail only; always-rescale path). Uses kA-style frag KF.
#define ATTN_TILE(KF, KT)                                                     \
    do {                                                                      \
        const int jb = (KT) * 32;                                             \
        const unsigned short* vb_ = Vtg + (size_t)l5 * 1024 + jb + hi8;       \
        const bf16x8 vf00 = *(const bf16x8*)(vb_);                            \
        const bf16x8 vf01 = *(const bf16x8*)(vb_ + 16);                       \
        const bf16x8 vf10 = *(const bf16x8*)(vb_ + 32768);                    \
        const bf16x8 vf11 = *(const bf16x8*)(vb_ + 32768 + 16);               \
        f32x16 s = {0.f};                                                     \
        _Pragma("unroll")                                                     \
        for (int t = 0; t < 4; ++t)                                           \
            s = __builtin_amdgcn_mfma_f32_32x32x16_bf16(KF[t], qf[t], s, 0, 0, 0); \
        float p[16];                                                          \
        _Pragma("unroll")                                                     \
        for (int reg = 0; reg < 16; ++reg) {                                  \
            const int j = jb + (reg & 3) + 8 * (reg >> 2) + 4 * hi;           \
            p[reg] = fmaf(s[reg], 0.125f, tb[q - j + 127]);                   \
        }                                                                     \
        if (jb + 31 > qbase) {                                                \
            _Pragma("unroll")                                                 \
            for (int reg = 0; reg < 16; ++reg) {                              \
                const int j = jb + (reg & 3) + 8 * (reg >> 2) + 4 * hi;       \
                p[reg] = (j <= q) ? p[reg] : -1e30f;                          \
            }                                                                 \
        }                                                                     \
        float mx = p[0];                                                      \
        _Pragma("unroll")                                                     \
        for (int reg = 1; reg < 16; ++reg) mx = fmaxf(mx, p[reg]);            \
        mx = fmaxf(mx, __shfl_xor(mx, 32, 64));                               \
        if (!__all(mx <= mi + 8.f)) {                                         \
            const float mnew = fmaxf(mi, mx);                                 \
            const float alpha = __expf(mi - mnew);                            \
            mi = mnew;                                                        \
            li *= alpha;                                                      \
            _Pragma("unroll")                                                 \
            for (int reg = 0; reg < 16; ++reg) {                              \
                oa0[reg] *= alpha;                                            \
                oa1[reg] *= alpha;                                            \
            }                                                                 \
        }                                                                     \
        float lsum = 0.f;                                                     \
        _Pragma("unroll")                                                     \
        for (int reg = 0; reg < 16; ++reg) {                                  \
            p[reg] = __expf(p[reg] - mi);                                     \
            lsum += p[reg];                                                   \
        }                                                                     \
        li += lsum;                                                           \
        const unsigned P0 = pk2(p[0], p[1]),   P1 = pk2(p[2], p[3]);          \
        const unsigned P2 = pk2(p[4], p[5]),   P3 = pk2(p[6], p[7]);          \
        const unsigned P4 = pk2(p[8], p[9]),   P5 = pk2(p[10], p[11]);        \
        const unsigned P6 = pk2(p[12], p[13]), P7 = pk2(p[14], p[15]);        \
        const unsigned R0 = __shfl_xor(hi ? P0 : P2, 32, 64);                 \
        const unsigned R1 = __shfl_xor(hi ? P1 : P3, 32, 64);                 \
        const unsigned R2 = __shfl_xor(hi ? P4 : P6, 32, 64);                 \
        const unsigned R3 = __shfl_xor(hi ? P5 : P7, 32, 64);                 \
        union { unsigned w[4]; bf16x8 v; } bq0, bq1;                          \
        bq0.w[0] = hi ? R0 : P0;  bq0.w[1] = hi ? R1 : P1;                    \
        bq0.w[2] = hi ? P2 : R0;  bq0.w[3] = hi ? P3 : R1;                    \
        bq1.w[0] = hi ? R2 : P4;  bq1.w[1] = hi ? R3 : P5;                    \
        bq1.w[2] = hi ? P6 : R2;  bq1.w[3] = hi ? P7 : R3;                    \
        oa0 = __builtin_amdgcn_mfma_f32_32x32x16_bf16(vf00, bq0.v, oa0, 0, 0, 0); \
        oa0 = __builtin_amdgcn_mfma_f32_32x32x16_bf16(vf01, bq1.v, oa0, 0, 0, 0); \
        oa1 = __builtin_amdgcn_mfma_f32_32x32x16_bf16(vf10, bq0.v, oa1, 0, 0, 0); \
        oa1 = __builtin_amdgcn_mfma_f32_32x32x16_bf16(vf11, bq1.v, oa1, 0, 0, 0); \
    } while (0)

// Pack+partner-exchange p[16] -> two PV B-frags (BQA, BQB).
#define PACKP(p, BQA, BQB)                                                    \
    do {                                                                      \
        const unsigned P0 = pk2(p[0], p[1]),   P1 = pk2(p[2], p[3]);          \
        const unsigned P2 = pk2(p[4], p[5]),   P3 = pk2(p[6], p[7]);          \
        const unsigned P4 = pk2(p[8], p[9]),   P5 = pk2(p[10], p[11]);        \
        const unsigned P6 = pk2(p[12], p[13]), P7 = pk2(p[14], p[15]);        \
        const unsigned R0 = __shfl_xor(hi ? P0 : P2, 32, 64);                 \
        const unsigned R1 = __shfl_xor(hi ? P1 : P3, 32, 64);                 \
        const unsigned R2 = __shfl_xor(hi ? P4 : P6, 32, 64);                 \
        const unsigned R3 = __shfl_xor(hi ? P5 : P7, 32, 64);                 \
        BQA.w[0] = hi ? R0 : P0;  BQA.w[1] = hi ? R1 : P1;                    \
        BQA.w[2] = hi ? P2 : R0;  BQA.w[3] = hi ? P3 : R1;                    \
        BQB.w[0] = hi ? R2 : P4;  BQB.w[1] = hi ? R3 : P5;                    \
        BQB.w[2] = hi ? P6 : R2;  BQB.w[3] = hi ? P7 : R3;                    \
    } while (0)

// Joint KVBLK=64: subtiles KT (kA) and KT+1 (kB); ONE softmax update.
#define ATTN_TILE2(KT)                                                        \
    do {                                                                      \
        const int jb = (KT) * 32;                                             \
        const unsigned short* vb_ = Vtg + (size_t)l5 * 1024 + jb + hi8;       \
        const bf16x8 vf00 = *(const bf16x8*)(vb_);                            \
        const bf16x8 vf01 = *(const bf16x8*)(vb_ + 16);                       \
        const bf16x8 vf02 = *(const bf16x8*)(vb_ + 32);                       \
        const bf16x8 vf03 = *(const bf16x8*)(vb_ + 48);                       \
        const bf16x8 vf10 = *(const bf16x8*)(vb_ + 32768);                    \
        const bf16x8 vf11 = *(const bf16x8*)(vb_ + 32768 + 16);               \
        const bf16x8 vf12 = *(const bf16x8*)(vb_ + 32768 + 32);               \
        const bf16x8 vf13 = *(const bf16x8*)(vb_ + 32768 + 48);               \
        f32x16 s0v = {0.f}, s1v = {0.f};                                      \
        _Pragma("unroll")                                                     \
        for (int t = 0; t < 4; ++t) {                                         \
            s0v = __builtin_amdgcn_mfma_f32_32x32x16_bf16(kA[t], qf[t], s0v, 0, 0, 0); \
            s1v = __builtin_amdgcn_mfma_f32_32x32x16_bf16(kB[t], qf[t], s1v, 0, 0, 0); \
        }                                                                     \
        if ((KT) + 2 < nt) LOADK(kA, (KT) + 2);                               \
        if ((KT) + 3 < nt) LOADK(kB, (KT) + 3);                               \
        float p0[16], p1[16];                                                 \
        _Pragma("unroll")                                                     \
        for (int reg = 0; reg < 16; ++reg) {                                  \
            const int jo = (reg & 3) + 8 * (reg >> 2) + 4 * hi;               \
            p0[reg] = fmaf(s0v[reg], 0.125f, tb[q - jb - jo + 127]);          \
            p1[reg] = fmaf(s1v[reg], 0.125f, tb[q - jb - 32 - jo + 127]);     \
        }                                                                     \
        if (jb + 63 > qbase) {                                                \
            _Pragma("unroll")                                                 \
            for (int reg = 0; reg < 16; ++reg) {                              \
                const int jo = (reg & 3) + 8 * (reg >> 2) + 4 * hi;           \
                p0[reg] = (jb + jo <= q) ? p0[reg] : -1e30f;                  \
                p1[reg] = (jb + 32 + jo <= q) ? p1[reg] : -1e30f;             \
            }                                                                 \
        }                                                                     \
        float mx = p0[0];                                                     \
        _Pragma("unroll")                                                     \
        for (int reg = 1; reg < 16; ++reg) mx = fmaxf(mx, p0[reg]);           \
        _Pragma("unroll")                                                     \
        for (int reg = 0; reg < 16; ++reg) mx = fmaxf(mx, p1[reg]);           \
        mx = fmaxf(mx, __shfl_xor(mx, 32, 64));                               \
        if (!__all(mx <= mi + 8.f)) {                                         \
            const float mnew = fmaxf(mi, mx);                                 \
            const float alpha = __expf(mi - mnew);                            \
            mi = mnew;                                                        \
            li *= alpha;                                                      \
            _Pragma("unroll")                                                 \
            for (int reg = 0; reg < 16; ++reg) {                              \
                oa0[reg] *= alpha;                                            \
                oa1[reg] *= alpha;                                            \
            }                                                                 \
        }                                                                     \
        float lsum = 0.f;                                                     \
        _Pragma("unroll")                                                     \
        for (int reg = 0; reg < 16; ++reg) {                                  \
            p0[reg] = __expf(p0[reg] - mi);                                   \
            p1[reg] = __expf(p1[reg] - mi);                                   \
            lsum += p0[reg] + p1[reg];                                        \
        }                                                                     \
        li += lsum;                                                           \
        union { unsigned w[4]; bf16x8 v; } bq00, bq01, bq10, bq11;            \
        PACKP(p0, bq00, bq01);                                                \
        PACKP(p1, bq10, bq11);                                                \
        oa0 = __builtin_amdgcn_mfma_f32_32x32x16_bf16(vf00, bq00.v, oa0, 0, 0, 0); \
        oa1 = __builtin_amdgcn_mfma_f32_32x32x16_bf16(vf10, bq00.v, oa1, 0, 0, 0); \
        oa0 = __builtin_amdgcn_mfma_f32_32x32x16_bf16(vf01, bq01.v, oa0, 0, 0, 0); \
        oa1 = __builtin_amdgcn_mfma_f32_32x32x16_bf16(vf11, bq01.v, oa1, 0, 0, 0); \
        oa0 = __builtin_amdgcn_mfma_f32_32x32x16_bf16(vf02, bq10.v, oa0, 0, 0, 0); \
        oa1 = __builtin_amdgcn_mfma_f32_32x32x16_bf16(vf12, bq10.v, oa1, 0, 0, 0); \
        oa0 = __builtin_amdgcn_mfma_f32_32x32x16_bf16(vf03, bq11.v, oa0, 0, 0, 0); \
        oa1 = __builtin_amdgcn_mfma_f32_32x32x16_bf16(vf13, bq11.v, oa1, 0, 0, 0); \
    } while (0)

__global__ __launch_bounds__(128) void attn_mfma(const unsigned short* __restrict__ qkvb,
                                                 const float* __restrict__ table,
                                                 unsigned short* __restrict__ y) {
    const int bh = blockIdx.x, b = bh >> 4, h = bh & 15;
    const int level = 15 - blockIdx.y;      // 15..0, longest blocks first
    const int tid = threadIdx.x, lane = tid & 63, wave = tid >> 6;  // wave 0..1
    const int l5 = lane & 31, hi = lane >> 5, hi8 = hi * 8;

    __shared__ float tb[1152];

    const unsigned short* Qg  = qkvb + ((size_t)(b)*16 + h) * 65536;       // [t][d]
    const unsigned short* Kg  = qkvb + ((size_t)(4 + b)*16 + h) * 65536;   // [t][d]
    const unsigned short* Vtg = qkvb + ((size_t)(8 + b)*16 + h) * 65536;   // [d][t]

    const int qbase = 64 * level + 32 * wave;
    const int q = qbase + l5;               // ONE query per lane
    const int nt = 2 * level + wave + 1;    // exact causal 32-j tile count

    // Q fragment (MFMA B-operand): B[col=q][k = t*16 + hi*8 + e]
    bf16x8 qf[4];
    {
        const unsigned short* qr = Qg + (size_t)q * 64 + hi8;
#pragma unroll
        for (int t = 0; t < 4; ++t) qf[t] = *(const bf16x8*)(qr + t * 16);
    }

    // tb[i] = table[(896+i)*16+h]; needed i = q-j+127 in [96, 64*level+190]
    const int tbn = 64 * level + 191;
    for (int i = tid; i < tbn; i += 128) tb[i] = table[(896 + i) * 16 + h];
    __syncthreads();  // tb ready; only block-wide sync in the kernel

    f32x16 oa0 = {0.f}, oa1 = {0.f};  // O^T d-halves: row d, col q (own lane)
    float mi = -1e30f, li = 0.f;

    bf16x8 kA[4], kB[4];
    LOADK(kA, 0);
    LOADK(kB, nt > 1 ? 1 : 0);
    int kt = 0;
    for (; kt + 1 < nt; kt += 2) ATTN_TILE2(kt);
    if (kt < nt) ATTN_TILE(kA, kt);  // odd-nt tail (kA prefetched by pair loop)

    // epilogue: li = own + partner halves (1 shfl); O^T/li -> y.
    li += __shfl_xor(li, 32, 64);
    const float linv = 1.0f / li;
    // lane's d = dh*32 + 8*g + 4*hi + (0..3)  (reg = 4g..4g+3 consecutive)
    unsigned short* yq = y + ((size_t)(b * 1024 + q)) * 1024 + h * 64;
#pragma unroll
    for (int g = 0; g < 4; ++g) {
        union { unsigned short u[4]; int2 v; } o4a, o4b;
#pragma unroll
        for (int i = 0; i < 4; ++i) {
            o4a.u[i] = f2bf(oa0[4 * g + i] * linv);
            o4b.u[i] = f2bf(oa1[4 * g + i] * linv);
        }
        *(int2*)(yq + 8 * g + 4 * hi) = o4a.v;
        *(int2*)(yq + 32 + 8 * g + 4 * hi) = o4b.v;
    }
}

extern "C" void kernel_launch(void* const* d_in, const int* in_sizes, int n_in,
                              void* d_out, int out_size, void* d_ws, size_t ws_size,
                              hipStream_t stream) {
    const float* x      = (const float*)d_in[0];
    const float* qkv_w  = (const float*)d_in[1];
    const float* qkv_b  = (const float*)d_in[2];
    const float* proj_w = (const float*)d_in[3];
    const float* proj_b = (const float*)d_in[4];
    const float* rel    = (const float*)d_in[5];
    float* out = (float*)d_out;

    char* ws = (char*)d_ws;
    unsigned short* xb   = (unsigned short*)(ws + 0);
    unsigned short* qwb  = (unsigned short*)(ws + 8388608);
    unsigned short* pwb  = (unsigned short*)(ws + 14680064);
    float* table         = (float*)(ws + 16777216);
    unsigned short* qkvb = (unsigned short*)(ws + 16908288);
    unsigned short* yb   = (unsigned short*)(ws + 42074112);

    cvt3<<<4096, 256, 0, stream>>>(x, qkv_w, proj_w, xb, qwb, pwb);
    table_reduce<<<2047, 1024, 0, stream>>>(rel, table);
    gemm_bt<0><<<dim3(32, 24), 512, 0, stream>>>(xb, qwb, qkv_b, qkvb, nullptr,
                                                 4096, 3072, 1024);
    attn_mfma<<<dim3(64, 16), 128, 0, stream>>>(qkvb, table, yb);
    gemm_bt<1><<<dim3(32, 8), 512, 0, stream>>>(yb, pwb, proj_b, nullptr, out,
                                                4096, 1024, 1024);
}